// Round 3
// baseline (12288.054 us; speedup 1.0000x reference)
//
#include <hip/hip_runtime.h>
#include <hip/hip_bf16.h>

#define S_LEN 2048
#define NB    32
#define NK    512     // IN_DIM == HID == 512
#define NH    512
#define N4H   2048
#define NWG   64
#define JPW   8       // hidden columns per WG

typedef __attribute__((ext_vector_type(8)))  short    short8;
typedef __attribute__((ext_vector_type(4)))  float    floatx4;
typedef __attribute__((ext_vector_type(16))) float    floatx16;
typedef __attribute__((ext_vector_type(4)))  unsigned uintx4;

__device__ __forceinline__ short f2bf(float f) {
  union { float f; unsigned u; } v; v.f = f;
  unsigned r = v.u + 0x7fffu + ((v.u >> 16) & 1u);
  return (short)(r >> 16);
}

__device__ __forceinline__ float sigm(float x) { return 1.f / (1.f + __expf(-x)); }

__global__ __launch_bounds__(256, 1) void plstm_persist(
    const float* __restrict__ X,  const float* __restrict__ Wx, const float* __restrict__ bx,
    const float* __restrict__ Wh, const float* __restrict__ bh, const float* __restrict__ zc,
    float* __restrict__ out, unsigned* __restrict__ flags,   // 64 packed 4B flags
    unsigned long long* __restrict__ hbuf)                   // 2 x 32KB bf16 h (row-major 32x512)
{
  const int tid  = threadIdx.x;
  const int g    = blockIdx.x;
  const int wv   = tid >> 6;
  const int lane = tid & 63;
  const int jbase = g * JPW;

  const int colN  = lane & 31;        // n_local = q*8+jj
  const int kgrp  = lane >> 5;
  const int qgate = colN >> 3;
  const int jj    = colN & 7;
  const int nglob = qgate * NH + jbase + jj;
  const int arow  = lane & 31;        // batch row for A frags

  // B-fragments (weights) resident in registers for this wave's K-quarter
  short8 wxr[8], whr[8];
  #pragma unroll
  for (int it = 0; it < 8; ++it) {
    const int k0 = wv * 128 + it * 16 + kgrp * 8;
    short8 a, b;
    #pragma unroll
    for (int e = 0; e < 8; ++e) {
      a[e] = f2bf(Wx[(size_t)(k0 + e) * N4H + nglob]);
      b[e] = f2bf(Wh[(size_t)(k0 + e) * N4H + nglob]);
    }
    wxr[it] = a; whr[it] = b;
  }

  // per-thread elementwise ownership: (batch m_own, hidden jbase+j_own)
  const int m_own = tid >> 3;   // 0..31
  const int j_own = tid & 7;    // 0..7
  float bsum[4];
  #pragma unroll
  for (int q = 0; q < 4; ++q)
    bsum[q] = bx[q * NH + jbase + j_own] + bh[q * NH + jbase + j_own];
  const float zcv = zc[jbase + j_own];
  float cstate = 0.f;

  __shared__ float lds_acc[4][32][36];                 // pad 36: reduce-read 2-way (free)
  __shared__ __align__(16) unsigned short lds_hs[32][8];

  // ---- prologue: X[0] fragments into registers ----
  short8 xf[8];
  {
    const floatx4* p0 = (const floatx4*)(X + arow * NK);
    #pragma unroll
    for (int it = 0; it < 8; ++it) {
      const int k0 = wv * 128 + it * 16 + kgrp * 8;
      floatx4 x0 = p0[k0 >> 2], x1 = p0[(k0 >> 2) + 1];
      short8 a;
      #pragma unroll
      for (int e = 0; e < 4; ++e) { a[e] = f2bf(x0[e]); a[4 + e] = f2bf(x1[e]); }
      xf[it] = a;
    }
  }

  for (int t = 0; t < S_LEN; ++t) {
    floatx16 acc;
    #pragma unroll
    for (int r = 0; r < 16; ++r) acc[r] = 0.f;

    // ---- input-projection MFMAs first: independent of h, overlaps producers ----
    #pragma unroll
    for (int it = 0; it < 8; ++it)
      acc = __builtin_amdgcn_mfma_f32_32x32x16_bf16(xf[it], wxr[it], acc, 0, 0, 0);

    floatx4 xnew[16];

    if (t > 0) {
      // ---- per-wave fine-grained wait: only this wave's 16 producers ----
      if (lane < 16) {
        const unsigned* f = &flags[wv * 16 + lane];   // one 64B line per wave
        while (__hip_atomic_load(f, __ATOMIC_RELAXED, __HIP_MEMORY_SCOPE_AGENT)
               < (unsigned)t) { }
      }
      asm volatile("" ::: "memory");   // compiler fence: keep h loads below the poll

      // ---- h-slice loads: 8 x 16B agent-coherent (sc1) loads, one wait ----
      const char* hb = (const char*)hbuf + (size_t)((t - 1) & 1) * 32768;
      const char* ap = hb + arow * 1024 + wv * 256 + kgrp * 16;
      uintx4 h0, h1, h2, h3, h4, h5, h6, h7;
      asm volatile(
        "global_load_dwordx4 %0, %[p], off sc1\n\t"
        "global_load_dwordx4 %1, %[p], off offset:32 sc1\n\t"
        "global_load_dwordx4 %2, %[p], off offset:64 sc1\n\t"
        "global_load_dwordx4 %3, %[p], off offset:96 sc1\n\t"
        "global_load_dwordx4 %4, %[p], off offset:128 sc1\n\t"
        "global_load_dwordx4 %5, %[p], off offset:160 sc1\n\t"
        "global_load_dwordx4 %6, %[p], off offset:192 sc1\n\t"
        "global_load_dwordx4 %7, %[p], off offset:224 sc1\n\t"
        "s_waitcnt vmcnt(0)"
        : "=&v"(h0), "=&v"(h1), "=&v"(h2), "=&v"(h3),
          "=&v"(h4), "=&v"(h5), "=&v"(h6), "=&v"(h7)
        : [p] "v"(ap)
        : "memory");

      // ---- issue X[t+1] prefetch now: hides under MFMAs + reduce + publish ----
      if (t + 1 < S_LEN) {
        const floatx4* p = (const floatx4*)(X + (size_t)(t + 1) * NB * NK + arow * NK);
        #pragma unroll
        for (int it = 0; it < 8; ++it) {
          const int k0 = wv * 128 + it * 16 + kgrp * 8;
          xnew[2 * it]     = p[k0 >> 2];
          xnew[2 * it + 1] = p[(k0 >> 2) + 1];
        }
      }

      // ---- recurrent MFMAs ----
      uintx4 hq[8] = { h0, h1, h2, h3, h4, h5, h6, h7 };
      #pragma unroll
      for (int it = 0; it < 8; ++it) {
        union { uintx4 u; short8 s; } cv; cv.u = hq[it];
        acc = __builtin_amdgcn_mfma_f32_32x32x16_bf16(cv.s, whr[it], acc, 0, 0, 0);
      }
    } else {
      // t==0: prefetch X[1]
      const floatx4* p = (const floatx4*)(X + (size_t)NB * NK + arow * NK);
      #pragma unroll
      for (int it = 0; it < 8; ++it) {
        const int k0 = wv * 128 + it * 16 + kgrp * 8;
        xnew[2 * it]     = p[k0 >> 2];
        xnew[2 * it + 1] = p[(k0 >> 2) + 1];
      }
    }

    // ---- cross-wave partial reduction via LDS ----
    #pragma unroll
    for (int r = 0; r < 16; ++r) {
      const int row = (r & 3) + 8 * (r >> 2) + 4 * kgrp;   // verified 32x32 C/D layout
      lds_acc[wv][row][colN] = acc[r];
    }
    __syncthreads();

    float pre[4];
    #pragma unroll
    for (int q = 0; q < 4; ++q) {
      const int cc = q * 8 + j_own;
      pre[q] = lds_acc[0][m_own][cc] + lds_acc[1][m_own][cc]
             + lds_acc[2][m_own][cc] + lds_acc[3][m_own][cc] + bsum[q];
    }
    const float iv = sigm(pre[0]);
    const float ov = sigm(pre[1]);
    const float fv = sigm(pre[3]);
    const float zv = tanhf(pre[2] + zcv * cstate);   // peephole on block input
    cstate = iv * zv + fv * cstate;
    const float hv = ov * tanhf(cstate);

    // ---- publish h_t ASAP: LDS gather -> 32 x 16B sc1 stores -> flag ----
    lds_hs[m_own][j_own] = (unsigned short)f2bf(hv);
    __syncthreads();

    if (tid < 32) {
      uintx4 u = *(const uintx4*)&lds_hs[tid][0];          // row tid, 16B
      char* sp = (char*)hbuf + (size_t)(t & 1) * 32768 + tid * 1024 + jbase * 2;
      asm volatile(
        "global_store_dwordx4 %[p], %[d], off sc1\n\t"
        "s_waitcnt vmcnt(0)"
        :: [p] "v"(sp), [d] "v"(u)
        : "memory");
      if (tid == 0)
        __hip_atomic_store(&flags[g], (unsigned)(t + 1),
                           __ATOMIC_RELAXED, __HIP_MEMORY_SCOPE_AGENT);
    }

    // ---- sinks: off the critical path ----
    out[((size_t)t * NB + m_own) * NH + jbase + j_own] = hv;
    if (t == S_LEN - 1) {
      out[(size_t)S_LEN * NB * NH + (size_t)m_own * NH + jbase + j_own] = hv;
      out[(size_t)S_LEN * NB * NH + (size_t)NB * NH + (size_t)m_own * NH + jbase + j_own] = cstate;
    }

    // ---- convert X prefetch for next step ----
    if (t + 1 < S_LEN) {
      #pragma unroll
      for (int it = 0; it < 8; ++it) {
        short8 a;
        #pragma unroll
        for (int e = 0; e < 4; ++e) {
          a[e]     = f2bf(xnew[2 * it][e]);
          a[4 + e] = f2bf(xnew[2 * it + 1][e]);
        }
        xf[it] = a;
      }
    }
  }
}

extern "C" void kernel_launch(void* const* d_in, const int* in_sizes, int n_in,
                              void* d_out, int out_size, void* d_ws, size_t ws_size,
                              hipStream_t stream) {
  const float* X  = (const float*)d_in[0];
  const float* Wx = (const float*)d_in[1];
  const float* bx = (const float*)d_in[2];
  const float* Wh = (const float*)d_in[3];
  const float* bh = (const float*)d_in[4];
  const float* zc = (const float*)d_in[5];
  float* out = (float*)d_out;
  unsigned* flags = (unsigned*)d_ws;                                   // 64 packed flags
  unsigned long long* hbuf = (unsigned long long*)((char*)d_ws + 4096); // 2 x 32KB bf16 h

  hipMemsetAsync(d_ws, 0, 4096, stream);  // flags must start at 0 every launch
  hipLaunchKernelGGL(plstm_persist, dim3(NWG), dim3(256), 0, stream,
                     X, Wx, bx, Wh, bh, zc, out, flags, hbuf);
}

// Round 5
// 10252.698 us; speedup vs baseline: 1.1985x; 1.1985x over previous
//
#include <hip/hip_runtime.h>
#include <hip/hip_bf16.h>

#define S_LEN 2048
#define NB    32
#define NK    512     // IN_DIM == HID == 512
#define NH    512
#define N4H   2048
#define NWG   64
#define JPW   8       // hidden columns per WG

typedef __attribute__((ext_vector_type(8)))  short    short8;
typedef __attribute__((ext_vector_type(4)))  float    floatx4;
typedef __attribute__((ext_vector_type(16))) float    floatx16;
typedef __attribute__((ext_vector_type(4)))  unsigned uintx4;

__device__ __forceinline__ short f2bf(float f) {
  union { float f; unsigned u; } v; v.f = f;
  unsigned r = v.u + 0x7fffu + ((v.u >> 16) & 1u);
  return (short)(r >> 16);
}
__device__ __forceinline__ float sigm(float x) { return 1.f / (1.f + __expf(-x)); }
__device__ __forceinline__ float ftanh(float x) {
  float e = __expf(2.f * x);
  return 1.f - 2.f / (e + 1.f);
}

// 16 x 16B poll-loads of this lane's h slice (fp32, tagged), no wait.
#define HLOAD16                                                         \
  asm volatile(                                                         \
    "global_load_dwordx4 %0,  %[p], off sc1\n\t"                        \
    "global_load_dwordx4 %1,  %[p], off offset:16 sc1\n\t"              \
    "global_load_dwordx4 %2,  %[p], off offset:64 sc1\n\t"              \
    "global_load_dwordx4 %3,  %[p], off offset:80 sc1\n\t"              \
    "global_load_dwordx4 %4,  %[p], off offset:128 sc1\n\t"             \
    "global_load_dwordx4 %5,  %[p], off offset:144 sc1\n\t"             \
    "global_load_dwordx4 %6,  %[p], off offset:192 sc1\n\t"             \
    "global_load_dwordx4 %7,  %[p], off offset:208 sc1\n\t"             \
    "global_load_dwordx4 %8,  %[p], off offset:256 sc1\n\t"             \
    "global_load_dwordx4 %9,  %[p], off offset:272 sc1\n\t"             \
    "global_load_dwordx4 %10, %[p], off offset:320 sc1\n\t"             \
    "global_load_dwordx4 %11, %[p], off offset:336 sc1\n\t"             \
    "global_load_dwordx4 %12, %[p], off offset:384 sc1\n\t"             \
    "global_load_dwordx4 %13, %[p], off offset:400 sc1\n\t"             \
    "global_load_dwordx4 %14, %[p], off offset:448 sc1\n\t"             \
    "global_load_dwordx4 %15, %[p], off offset:464 sc1"                 \
    : "=&v"(h0), "=&v"(h1), "=&v"(h2),  "=&v"(h3),                      \
      "=&v"(h4), "=&v"(h5), "=&v"(h6),  "=&v"(h7),                      \
      "=&v"(h8), "=&v"(h9), "=&v"(h10), "=&v"(h11),                     \
      "=&v"(h12), "=&v"(h13), "=&v"(h14), "=&v"(h15)                    \
    : [p] "v"(ap) : "memory")

#define CHK(x) bad |= ((x[0]^e8)&255u)|((x[1]^e8)&255u)|((x[2]^e8)&255u)|((x[3]^e8)&255u)

__global__ __launch_bounds__(256, 1) void plstm_persist(
    const float* __restrict__ X,  const float* __restrict__ Wx, const float* __restrict__ bx,
    const float* __restrict__ Wh, const float* __restrict__ bh, const float* __restrict__ zc,
    float* __restrict__ out, float* __restrict__ hbuf)   // 2 x 64KB fp32 h (32x512), tagged
{
  const int tid  = threadIdx.x;
  const int g    = blockIdx.x;
  const int wv   = tid >> 6, lane = tid & 63;
  const int colN = lane & 31, kgrp = lane >> 5;
  const int arow = colN;
  const int jbase = g * JPW;

  // B-fragments (weights) resident in registers for this wave's K-quarter
  const int qgate = colN >> 3, jj = colN & 7;
  const int nglob = qgate * NH + jbase + jj;
  short8 wxr[8], whr[8];
  #pragma unroll
  for (int it = 0; it < 8; ++it) {
    const int k0 = wv * 128 + it * 16 + kgrp * 8;
    short8 a, b;
    #pragma unroll
    for (int e = 0; e < 8; ++e) {
      a[e] = f2bf(Wx[(size_t)(k0 + e) * N4H + nglob]);
      b[e] = f2bf(Wh[(size_t)(k0 + e) * N4H + nglob]);
    }
    wxr[it] = a; whr[it] = b;
  }

  // elementwise ownership: (batch m_own, hidden jbase+j_own)
  const int m_own = tid >> 3;
  const int j_own = tid & 7;
  float bsum[4];
  #pragma unroll
  for (int q = 0; q < 4; ++q)
    bsum[q] = bx[q * NH + jbase + j_own] + bh[q * NH + jbase + j_own];
  const float zcv = zc[jbase + j_own];
  float cstate = 0.f;

  // parity-double-buffered reduce scratch: no back-edge barrier needed
  __shared__ float lds_acc[2][4][32][36];

  // prologue: X[0] fragments
  short8 xf[8];
  {
    const floatx4* p0 = (const floatx4*)(X + arow * NK);
    #pragma unroll
    for (int it = 0; it < 8; ++it) {
      const int k0 = wv * 128 + it * 16 + kgrp * 8;
      floatx4 x0 = p0[k0 >> 2], x1 = p0[(k0 >> 2) + 1];
      short8 a;
      #pragma unroll
      for (int e = 0; e < 4; ++e) { a[e] = f2bf(x0[e]); a[4+e] = f2bf(x1[e]); }
      xf[it] = a;
    }
  }

  floatx4 xnew[16];

  for (int t = 0; t < S_LEN; ++t) {
    const int par = t & 1;
    uintx4 h0, h1, h2, h3, h4, h5, h6, h7, h8, h9, h10, h11, h12, h13, h14, h15;
    const char* ap = (const char*)hbuf + (size_t)((t - 1) & 1) * 65536
                   + arow * 2048 + wv * 512 + kgrp * 32;

    if (t > 0) {
      HLOAD16;                       // issue poll loads immediately (no wait)
      // convert last step's X prefetch while loads are in flight
      #pragma unroll
      for (int it = 0; it < 8; ++it) {
        short8 a;
        #pragma unroll
        for (int e = 0; e < 4; ++e) {
          a[e]   = f2bf(xnew[2*it][e]);
          a[4+e] = f2bf(xnew[2*it+1][e]);
        }
        xf[it] = a;
      }
    }

    floatx16 acc;
    #pragma unroll
    for (int r = 0; r < 16; ++r) acc[r] = 0.f;

    // input-projection MFMAs (independent of h)
    #pragma unroll
    for (int it = 0; it < 8; ++it)
      acc = __builtin_amdgcn_mfma_f32_32x32x16_bf16(xf[it], wxr[it], acc, 0, 0, 0);

    if (t > 0) {
      // ---- poll own data until every dword carries step-(t-1)'s tag ----
      const unsigned e8 = (((unsigned)(t - 1) >> 1) + 1u) & 255u;
      for (;;) {
        asm volatile("s_waitcnt vmcnt(0)" ::: "memory");
        __builtin_amdgcn_sched_barrier(0);
        unsigned bad = 0u;
        CHK(h0);  CHK(h1);  CHK(h2);  CHK(h3);
        CHK(h4);  CHK(h5);  CHK(h6);  CHK(h7);
        CHK(h8);  CHK(h9);  CHK(h10); CHK(h11);
        CHK(h12); CHK(h13); CHK(h14); CHK(h15);
        if (!__any((int)(bad != 0u))) break;
        HLOAD16;
      }
      // ---- convert + recurrent MFMAs ----
      uintx4 hq[16] = { h0, h1, h2, h3, h4, h5, h6, h7,
                        h8, h9, h10, h11, h12, h13, h14, h15 };
      #pragma unroll
      for (int it = 0; it < 8; ++it) {
        short8 a;
        #pragma unroll
        for (int e = 0; e < 4; ++e) {
          a[e]   = f2bf(__uint_as_float(hq[2*it][e]));
          a[4+e] = f2bf(__uint_as_float(hq[2*it+1][e]));
        }
        acc = __builtin_amdgcn_mfma_f32_32x32x16_bf16(a, whr[it], acc, 0, 0, 0);
      }
    }

    // ---- cross-wave reduction (parity-buffered) ----
    #pragma unroll
    for (int r = 0; r < 16; ++r) {
      const int row = (r & 3) + 8 * (r >> 2) + 4 * kgrp;   // verified 32x32 C/D layout
      lds_acc[par][wv][row][colN] = acc[r];
    }
    __syncthreads();

    float pre[4];
    #pragma unroll
    for (int q = 0; q < 4; ++q) {
      const int cc = q * 8 + j_own;
      pre[q] = lds_acc[par][0][m_own][cc] + lds_acc[par][1][m_own][cc]
             + lds_acc[par][2][m_own][cc] + lds_acc[par][3][m_own][cc] + bsum[q];
    }
    const float iv = sigm(pre[0]);
    const float ov = sigm(pre[1]);
    const float fv = sigm(pre[3]);
    const float zv = ftanh(pre[2] + zcv * cstate);   // peephole on block input
    cstate = iv * zv + fv * cstate;
    const float hv = ov * ftanh(cstate);

    // ---- publish h_t immediately: single tagged fp32 store, no ack ----
    if (t + 1 < S_LEN) {
      union { float f; unsigned u; } pv; pv.f = hv;
      pv.u = (pv.u & 0xffffff00u) | ((((unsigned)t >> 1) + 1u) & 255u);
      float* sp = hbuf + (size_t)par * 16384 + m_own * NH + jbase + j_own;
      asm volatile("global_store_dword %0, %1, off sc1"
                   :: "v"(sp), "v"(pv.u) : "memory");
    }

    // ---- X[t+1] prefetch (completes during next step's shadow) ----
    if (t + 1 < S_LEN) {
      const floatx4* p = (const floatx4*)(X + (size_t)(t + 1) * NB * NK + arow * NK);
      #pragma unroll
      for (int it = 0; it < 8; ++it) {
        const int k0 = wv * 128 + it * 16 + kgrp * 8;
        xnew[2 * it]     = p[k0 >> 2];
        xnew[2 * it + 1] = p[(k0 >> 2) + 1];
      }
    }

    // ---- output sinks (off critical path) ----
    out[((size_t)t * NB + m_own) * NH + jbase + j_own] = hv;
    if (t == S_LEN - 1) {
      out[(size_t)S_LEN * NB * NH + (size_t)m_own * NH + jbase + j_own] = hv;
      out[(size_t)S_LEN * NB * NH + (size_t)NB * NH + (size_t)m_own * NH + jbase + j_own] = cstate;
    }
  }
}

extern "C" void kernel_launch(void* const* d_in, const int* in_sizes, int n_in,
                              void* d_out, int out_size, void* d_ws, size_t ws_size,
                              hipStream_t stream) {
  const float* X  = (const float*)d_in[0];
  const float* Wx = (const float*)d_in[1];
  const float* bx = (const float*)d_in[2];
  const float* Wh = (const float*)d_in[3];
  const float* bh = (const float*)d_in[4];
  const float* zc = (const float*)d_in[5];
  float* out  = (float*)d_out;
  float* hbuf = (float*)d_ws;    // 2 x 64KB tagged fp32 h; no init needed (tags self-validate)

  hipLaunchKernelGGL(plstm_persist, dim3(NWG), dim3(256), 0, stream,
                     X, Wx, bx, Wh, bh, zc, out, hbuf);
}